// Round 2
// baseline (733.216 us; speedup 1.0000x reference)
//
#include <hip/hip_runtime.h>
#include <hip/hip_bf16.h>

#define N_NODES 50000
#define N_EDGES 800000
#define F_IN    500
#define HID     128
#define NCLS    10

// ---------------- CSR build ----------------

__global__ __launch_bounds__(256) void count_deg_k(const int* dst, int* cnt) {
    int e = blockIdx.x * 256 + threadIdx.x;
    if (e < N_EDGES) atomicAdd(&cnt[dst[e]], 1);
}

__global__ __launch_bounds__(256) void compute_dis_k(const int* cnt, float* dis) {
    int i = blockIdx.x * 256 + threadIdx.x;
    if (i < N_NODES) {
        float deg = (float)(cnt[i] + 1);   // +1 self loop
        dis[i] = rsqrtf(deg);
    }
}

__global__ __launch_bounds__(1024) void scan_k(const int* cnt, int* off) {
    __shared__ int part[1024];
    const int PER = 49;  // ceil(50000/1024)
    int tid = threadIdx.x;
    int base = tid * PER;
    int s = 0;
    for (int i = 0; i < PER; ++i) {
        int idx = base + i;
        if (idx < N_NODES) s += cnt[idx];
    }
    part[tid] = s;
    __syncthreads();
    // Hillis-Steele inclusive scan
    for (int o = 1; o < 1024; o <<= 1) {
        int v = (tid >= o) ? part[tid - o] : 0;
        __syncthreads();
        part[tid] += v;
        __syncthreads();
    }
    int run = part[tid] - s;  // exclusive prefix
    for (int i = 0; i < PER; ++i) {
        int idx = base + i;
        if (idx < N_NODES) { off[idx] = run; run += cnt[idx]; }
    }
    if (tid == 1023) off[N_NODES] = N_EDGES;
}

__global__ __launch_bounds__(256) void fill_csr_k(const int* src, const int* dst,
                                                  const int* off, int* cur, int* csr) {
    int e = blockIdx.x * 256 + threadIdx.x;
    if (e < N_EDGES) {
        int d = dst[e];
        int p = off[d] + atomicAdd(&cur[d], 1);
        csr[p] = src[e];
    }
}

// ---------------- f32 GEMM: Out[M,128] = A[M,K] @ W[K,128] ----------------
// 64x128 tile per block (256 thr), 4 rows x 8 cols per thread, K chunks of 16.

#define KC 16
__global__ __launch_bounds__(256) void gemm_k(const float* __restrict__ A,
                                              const float* __restrict__ W,
                                              float* __restrict__ Out,
                                              int M, int K) {
    __shared__ float xs[KC][68];    // [k][row], padded
    __shared__ float ws[KC][132];   // [k][col], padded
    int tid = threadIdx.x;
    int tx = tid & 15;   // col group: 8 cols
    int ty = tid >> 4;   // row group: 4 rows
    int row0 = blockIdx.x * 64;

    float acc[4][8];
    #pragma unroll
    for (int i = 0; i < 4; ++i)
        #pragma unroll
        for (int j = 0; j < 8; ++j) acc[i][j] = 0.f;

    for (int k0 = 0; k0 < K; k0 += KC) {
        // stage A tile: 64 rows x 16 k  (transposed into xs[k][row])
        #pragma unroll
        for (int j = 0; j < 4; ++j) {
            int idx = tid + j * 256;      // 1024 = 64*16
            int r = idx >> 4, kk = idx & 15;
            int grow = row0 + r, gk = k0 + kk;
            float v = (grow < M && gk < K) ? A[(long)grow * K + gk] : 0.f;
            xs[kk][r] = v;
        }
        // stage W tile: 16 k x 128 cols
        #pragma unroll
        for (int j = 0; j < 8; ++j) {
            int idx = tid + j * 256;      // 2048 = 16*128
            int kk = idx >> 7, c = idx & 127;
            int gk = k0 + kk;
            float v = (gk < K) ? W[gk * 128 + c] : 0.f;
            ws[kk][c] = v;
        }
        __syncthreads();
        #pragma unroll
        for (int kk = 0; kk < KC; ++kk) {
            float a[4], b[8];
            #pragma unroll
            for (int i = 0; i < 4; ++i) a[i] = xs[kk][ty * 4 + i];
            #pragma unroll
            for (int j = 0; j < 8; ++j) b[j] = ws[kk][tx * 8 + j];
            #pragma unroll
            for (int i = 0; i < 4; ++i)
                #pragma unroll
                for (int j = 0; j < 8; ++j)
                    acc[i][j] = fmaf(a[i], b[j], acc[i][j]);
        }
        __syncthreads();
    }
    // store (float4 x2 per row)
    #pragma unroll
    for (int i = 0; i < 4; ++i) {
        int r = row0 + ty * 4 + i;
        if (r < M) {
            float4* p = (float4*)(Out + (long)r * 128 + tx * 8);
            p[0] = make_float4(acc[i][0], acc[i][1], acc[i][2], acc[i][3]);
            p[1] = make_float4(acc[i][4], acc[i][5], acc[i][6], acc[i][7]);
        }
    }
}

// ---------------- aggregation: one wave per node ----------------
// Hout[n] = relu( sum_{e: dst=n} Hin[src_e]*dis[src]*dis[n] + Hin[n]*dis[n]^2 + bias )
// Edge loop unrolled x4 with independent gathers for MLP.

__global__ __launch_bounds__(256) void agg_k(const float* __restrict__ Hin,
                                             float* __restrict__ Hout,
                                             const int* __restrict__ off,
                                             const int* __restrict__ csr,
                                             const float* __restrict__ dis,
                                             const float* __restrict__ bias) {
    int w = (blockIdx.x * 256 + threadIdx.x) >> 6;
    int lane = threadIdx.x & 63;
    if (w >= N_NODES) return;
    int n = w;
    int e0 = off[n], e1 = off[n + 1];
    float dn = dis[n];

    const float2* hn = (const float2*)(Hin + (long)n * HID);
    float2 hv = hn[lane];
    float sw = dn * dn;
    float ax = hv.x * sw, ay = hv.y * sw;

    int e = e0;
    for (; e + 4 <= e1; e += 4) {
        int s0 = csr[e + 0], s1 = csr[e + 1], s2 = csr[e + 2], s3 = csr[e + 3];
        float w0 = dis[s0] * dn, w1 = dis[s1] * dn, w2 = dis[s2] * dn, w3 = dis[s3] * dn;
        float2 m0 = ((const float2*)(Hin + (long)s0 * HID))[lane];
        float2 m1 = ((const float2*)(Hin + (long)s1 * HID))[lane];
        float2 m2 = ((const float2*)(Hin + (long)s2 * HID))[lane];
        float2 m3 = ((const float2*)(Hin + (long)s3 * HID))[lane];
        ax = fmaf(m0.x, w0, ax); ay = fmaf(m0.y, w0, ay);
        ax = fmaf(m1.x, w1, ax); ay = fmaf(m1.y, w1, ay);
        ax = fmaf(m2.x, w2, ax); ay = fmaf(m2.y, w2, ay);
        ax = fmaf(m3.x, w3, ax); ay = fmaf(m3.y, w3, ay);
    }
    for (; e < e1; ++e) {
        int s = csr[e];
        float wgt = dis[s] * dn;
        float2 m = ((const float2*)(Hin + (long)s * HID))[lane];
        ax = fmaf(m.x, wgt, ax);
        ay = fmaf(m.y, wgt, ay);
    }
    float2 bv = ((const float2*)bias)[lane];
    float ox = ax + bv.x, oy = ay + bv.y;
    ox = ox > 0.f ? ox : 0.f;
    oy = oy > 0.f ? oy : 0.f;
    ((float2*)(Hout + (long)n * HID))[lane] = make_float2(ox, oy);
}

// ---------------- head: logits = H @ Wo + bo, softmax ----------------

__global__ __launch_bounds__(256) void head_k(const float* __restrict__ Hf,
                                              const float* __restrict__ Wo,
                                              const float* __restrict__ bo,
                                              float* __restrict__ out) {
    __shared__ float wsh[HID * NCLS];
    __shared__ float bsh[NCLS];
    int tid = threadIdx.x;
    for (int i = tid; i < HID * NCLS; i += 256) wsh[i] = Wo[i];
    if (tid < NCLS) bsh[tid] = bo[tid];
    __syncthreads();

    int w = (blockIdx.x * 256 + tid) >> 6;
    int lane = tid & 63;
    if (w >= N_NODES) return;

    float h0 = Hf[(long)w * HID + lane];
    float h1 = Hf[(long)w * HID + 64 + lane];

    float logit[NCLS];
    #pragma unroll
    for (int c = 0; c < NCLS; ++c) {
        float p = h0 * wsh[lane * NCLS + c] + h1 * wsh[(lane + 64) * NCLS + c];
        #pragma unroll
        for (int o = 32; o > 0; o >>= 1) p += __shfl_xor(p, o);
        logit[c] = p + bsh[c];
    }
    if (lane == 0) {
        float m = logit[0];
        #pragma unroll
        for (int c = 1; c < NCLS; ++c) m = fmaxf(m, logit[c]);
        float es[NCLS]; float ssum = 0.f;
        #pragma unroll
        for (int c = 0; c < NCLS; ++c) { es[c] = __expf(logit[c] - m); ssum += es[c]; }
        float inv = 1.f / ssum;
        #pragma unroll
        for (int c = 0; c < NCLS; ++c) out[(long)w * NCLS + c] = es[c] * inv;
    }
}

// ---------------- launch ----------------

extern "C" void kernel_launch(void* const* d_in, const int* in_sizes, int n_in,
                              void* d_out, int out_size, void* d_ws, size_t ws_size,
                              hipStream_t stream) {
    const float* x   = (const float*)d_in[0];
    const int*   ei  = (const int*)d_in[1];
    const float* W1  = (const float*)d_in[2];
    const float* b1  = (const float*)d_in[3];
    const float* W2  = (const float*)d_in[4];
    const float* b2  = (const float*)d_in[5];
    const float* Wo  = (const float*)d_in[6];
    const float* bo  = (const float*)d_in[7];
    float* out = (float*)d_out;

    const int* srcp = ei;            // edge_index[0]
    const int* dstp = ei + N_EDGES;  // edge_index[1]

    // workspace layout
    char* wsb = (char*)d_ws;
    int*   cnt = (int*)wsb;                       wsb += sizeof(int) * N_NODES;
    int*   off = (int*)wsb;                       wsb += sizeof(int) * (N_NODES + 1);
    int*   cur = (int*)wsb;                       wsb += sizeof(int) * N_NODES;
    int*   csr = (int*)wsb;                       wsb += sizeof(int) * N_EDGES;
    float* dis = (float*)wsb;                     wsb += sizeof(float) * N_NODES;
    float* hA  = (float*)wsb;                     wsb += sizeof(float) * (size_t)N_NODES * HID;
    float* hB  = (float*)wsb;                     wsb += sizeof(float) * (size_t)N_NODES * HID;

    hipMemsetAsync(cnt, 0, sizeof(int) * N_NODES, stream);
    hipMemsetAsync(cur, 0, sizeof(int) * N_NODES, stream);

    int ebl = (N_EDGES + 255) / 256;
    int nbl = (N_NODES + 255) / 256;
    count_deg_k<<<ebl, 256, 0, stream>>>(dstp, cnt);
    compute_dis_k<<<nbl, 256, 0, stream>>>(cnt, dis);
    scan_k<<<1, 1024, 0, stream>>>(cnt, off);
    fill_csr_k<<<ebl, 256, 0, stream>>>(srcp, dstp, off, cur, csr);

    int gblocks = (N_NODES + 63) / 64;   // 782
    int wblocks = (N_NODES + 3) / 4;     // 12500 (4 waves/block, 1 wave/node)

    // layer 1
    gemm_k<<<gblocks, 256, 0, stream>>>(x, W1, hA, N_NODES, F_IN);
    agg_k<<<wblocks, 256, 0, stream>>>(hA, hB, off, csr, dis, b1);
    // layer 2
    gemm_k<<<gblocks, 256, 0, stream>>>(hB, W2, hA, N_NODES, HID);
    agg_k<<<wblocks, 256, 0, stream>>>(hA, hB, off, csr, dis, b2);
    // head
    head_k<<<wblocks, 256, 0, stream>>>(hB, Wo, bo, out);
}

// Round 3
// 469.847 us; speedup vs baseline: 1.5605x; 1.5605x over previous
//
#include <hip/hip_runtime.h>
#include <hip/hip_bf16.h>
#include <stdint.h>

#define N_NODES 50000
#define N_EDGES 800000
#define F_IN    500
#define HID     128
#define NCLS    10

typedef __attribute__((ext_vector_type(8))) short bf16x8;
typedef __attribute__((ext_vector_type(4))) float f32x4;

// ---------------- CSR build ----------------

__global__ __launch_bounds__(256) void count_deg_k(const int* dst, int* cnt) {
    int e = blockIdx.x * 256 + threadIdx.x;
    if (e < N_EDGES) atomicAdd(&cnt[dst[e]], 1);
}

__global__ __launch_bounds__(256) void compute_dis_k(const int* cnt, float* dis) {
    int i = blockIdx.x * 256 + threadIdx.x;
    if (i < N_NODES) {
        float deg = (float)(cnt[i] + 1);   // +1 self loop
        dis[i] = rsqrtf(deg);
    }
}

__global__ __launch_bounds__(1024) void scan_k(const int* __restrict__ cnt, int* __restrict__ off) {
    __shared__ int part[1024];
    const int PER = 52;  // 52*1024 = 53248 >= 50000, 52%4==0 for int4
    int tid = threadIdx.x;
    int base = tid * PER;
    int vals[PER];
    #pragma unroll
    for (int i = 0; i < PER; i += 4) {
        int idx = base + i;
        int4 v = make_int4(0, 0, 0, 0);
        if (idx + 3 < N_NODES) {
            v = *(const int4*)&cnt[idx];
        } else {
            if (idx + 0 < N_NODES) v.x = cnt[idx + 0];
            if (idx + 1 < N_NODES) v.y = cnt[idx + 1];
            if (idx + 2 < N_NODES) v.z = cnt[idx + 2];
            if (idx + 3 < N_NODES) v.w = cnt[idx + 3];
        }
        vals[i + 0] = v.x; vals[i + 1] = v.y; vals[i + 2] = v.z; vals[i + 3] = v.w;
    }
    int s = 0;
    #pragma unroll
    for (int i = 0; i < PER; ++i) s += vals[i];
    part[tid] = s;
    __syncthreads();
    // Hillis-Steele inclusive scan
    for (int o = 1; o < 1024; o <<= 1) {
        int v = (tid >= o) ? part[tid - o] : 0;
        __syncthreads();
        part[tid] += v;
        __syncthreads();
    }
    int run = part[tid] - s;  // exclusive prefix
    #pragma unroll
    for (int i = 0; i < PER; ++i) {
        int idx = base + i;
        if (idx < N_NODES) { off[idx] = run; run += vals[i]; }
    }
    if (tid == 1023) off[N_NODES] = N_EDGES;
}

__global__ __launch_bounds__(256) void fill_csr_k(const int* src, const int* dst,
                                                  const int* off, int* cur, int* csr) {
    int e = blockIdx.x * 256 + threadIdx.x;
    if (e < N_EDGES) {
        int d = dst[e];
        int p = off[d] + atomicAdd(&cur[d], 1);
        csr[p] = src[e];
    }
}

// ---------------- weight transpose+cast: W [K][128] -> WT bf16 [128][KPAD] ----------------

__global__ __launch_bounds__(256) void transpose_cast_k(const float* __restrict__ W,
                                                        __hip_bfloat16* __restrict__ WT,
                                                        int K, int KPAD) {
    int id = blockIdx.x * 256 + threadIdx.x;
    if (id >= 128 * KPAD) return;
    int n = id / KPAD;
    int k = id - n * KPAD;
    WT[id] = (k < K) ? __float2bfloat16(W[(long)k * 128 + n]) : __float2bfloat16(0.f);
}

// ---------------- MFMA GEMM: Out[M,128] = A[M,KREAL] @ BT[128,KPAD]^T ----------------
// A is f32 (cast to bf16 during staging); BT is pre-cast bf16, row n = column n of W.
// BM=64, BN=128, BK=64. 256 threads = 4 waves (2x2), wave tile 32x64.
// LDS rows padded +8 bf16 -> bank stride 36%32=4 -> ~2-way conflicts (free).

template<int KPAD, int KREAL>
__global__ __launch_bounds__(256) void gemm_mfma_k(const float* __restrict__ A,
                                                   const __hip_bfloat16* __restrict__ BT,
                                                   float* __restrict__ Out, int M) {
    __shared__ __hip_bfloat16 As[64][72];
    __shared__ __hip_bfloat16 Bs[128][72];
    const int tid  = threadIdx.x;
    const int row0 = blockIdx.x * 64;
    const int wid  = tid >> 6, lane = tid & 63;
    const int wr   = (wid >> 1) * 32;   // wave row offset in tile
    const int wc   = (wid & 1) * 64;    // wave col offset
    const int l15  = lane & 15;
    const int lk   = (lane >> 4) * 8;   // k offset of this lane's fragment

    f32x4 acc[2][4];
    #pragma unroll
    for (int i = 0; i < 2; ++i)
        #pragma unroll
        for (int j = 0; j < 4; ++j) acc[i][j] = (f32x4){0.f, 0.f, 0.f, 0.f};

    const int arow = tid >> 2;          // 0..63
    const int aseg = (tid & 3) * 16;    // k sub-offset 0/16/32/48
    const int brow = tid >> 1;          // 0..127
    const int bseg = (tid & 1) * 32;    // k sub-offset 0/32
    const bool rowok = (row0 + arow) < M;
    const float* aptr = A + (long)(row0 + arow) * KREAL;

    for (int k0 = 0; k0 < KPAD; k0 += 64) {
        // ---- stage A (f32 -> bf16) : 64 rows x 64 k ----
        {
            float v[16];
            const float* ap = aptr + k0 + aseg;
            if (rowok && (k0 + aseg + 16 <= KREAL)) {
                #pragma unroll
                for (int i = 0; i < 4; ++i) {
                    float4 f = ((const float4*)ap)[i];
                    v[i*4+0] = f.x; v[i*4+1] = f.y; v[i*4+2] = f.z; v[i*4+3] = f.w;
                }
            } else {
                #pragma unroll
                for (int i = 0; i < 16; ++i) {
                    int gk = k0 + aseg + i;
                    v[i] = (rowok && gk < KREAL) ? ap[i] : 0.f;
                }
            }
            __hip_bfloat16 bb[16];
            #pragma unroll
            for (int i = 0; i < 16; ++i) bb[i] = __float2bfloat16(v[i]);
            *(bf16x8*)&As[arow][aseg]     = *(bf16x8*)&bb[0];
            *(bf16x8*)&As[arow][aseg + 8] = *(bf16x8*)&bb[8];
        }
        // ---- stage B (bf16 copy) : 128 rows x 64 k ----
        {
            const __hip_bfloat16* bp = BT + (long)brow * KPAD + k0 + bseg;
            #pragma unroll
            for (int i = 0; i < 4; ++i)
                *(bf16x8*)&Bs[brow][bseg + i * 8] = ((const bf16x8*)bp)[i];
        }
        __syncthreads();
        #pragma unroll
        for (int kk = 0; kk < 64; kk += 32) {
            bf16x8 af[2], bfr[4];
            #pragma unroll
            for (int i = 0; i < 2; ++i)
                af[i] = *(const bf16x8*)&As[wr + i * 16 + l15][kk + lk];
            #pragma unroll
            for (int j = 0; j < 4; ++j)
                bfr[j] = *(const bf16x8*)&Bs[wc + j * 16 + l15][kk + lk];
            #pragma unroll
            for (int i = 0; i < 2; ++i)
                #pragma unroll
                for (int j = 0; j < 4; ++j)
                    acc[i][j] = __builtin_amdgcn_mfma_f32_16x16x32_bf16(af[i], bfr[j], acc[i][j], 0, 0, 0);
        }
        __syncthreads();
    }
    // ---- epilogue: C/D layout col=lane&15, row=(lane>>4)*4+reg ----
    const int r4 = (lane >> 4) * 4;
    #pragma unroll
    for (int i = 0; i < 2; ++i) {
        #pragma unroll
        for (int r = 0; r < 4; ++r) {
            int grow = row0 + wr + i * 16 + r4 + r;
            if (grow < M) {
                float* op = Out + (long)grow * 128 + wc + l15;
                #pragma unroll
                for (int j = 0; j < 4; ++j) op[j * 16] = acc[i][j][r];
            }
        }
    }
}

// ---------------- aggregation: one wave per node ----------------
// Hout[n] = relu( sum_{e: dst=n} Hin[src_e]*dis[src]*dis[n] + Hin[n]*dis[n]^2 + bias )

__global__ __launch_bounds__(256) void agg_k(const float* __restrict__ Hin,
                                             float* __restrict__ Hout,
                                             const int* __restrict__ off,
                                             const int* __restrict__ csr,
                                             const float* __restrict__ dis,
                                             const float* __restrict__ bias) {
    int w = (blockIdx.x * 256 + threadIdx.x) >> 6;
    int lane = threadIdx.x & 63;
    if (w >= N_NODES) return;
    int n = w;
    int e0 = off[n], e1 = off[n + 1];
    float dn = dis[n];

    const float2* hn = (const float2*)(Hin + (long)n * HID);
    float2 hv = hn[lane];
    float sw = dn * dn;
    float ax = hv.x * sw, ay = hv.y * sw;

    int e = e0;
    for (; e + 4 <= e1; e += 4) {
        int s0 = csr[e + 0], s1 = csr[e + 1], s2 = csr[e + 2], s3 = csr[e + 3];
        float w0 = dis[s0] * dn, w1 = dis[s1] * dn, w2 = dis[s2] * dn, w3 = dis[s3] * dn;
        float2 m0 = ((const float2*)(Hin + (long)s0 * HID))[lane];
        float2 m1 = ((const float2*)(Hin + (long)s1 * HID))[lane];
        float2 m2 = ((const float2*)(Hin + (long)s2 * HID))[lane];
        float2 m3 = ((const float2*)(Hin + (long)s3 * HID))[lane];
        ax = fmaf(m0.x, w0, ax); ay = fmaf(m0.y, w0, ay);
        ax = fmaf(m1.x, w1, ax); ay = fmaf(m1.y, w1, ay);
        ax = fmaf(m2.x, w2, ax); ay = fmaf(m2.y, w2, ay);
        ax = fmaf(m3.x, w3, ax); ay = fmaf(m3.y, w3, ay);
    }
    for (; e < e1; ++e) {
        int s = csr[e];
        float wgt = dis[s] * dn;
        float2 m = ((const float2*)(Hin + (long)s * HID))[lane];
        ax = fmaf(m.x, wgt, ax);
        ay = fmaf(m.y, wgt, ay);
    }
    float2 bv = ((const float2*)bias)[lane];
    float ox = ax + bv.x, oy = ay + bv.y;
    ox = ox > 0.f ? ox : 0.f;
    oy = oy > 0.f ? oy : 0.f;
    ((float2*)(Hout + (long)n * HID))[lane] = make_float2(ox, oy);
}

// ---------------- head: logits = H @ Wo + bo, softmax ----------------

__global__ __launch_bounds__(256) void head_k(const float* __restrict__ Hf,
                                              const float* __restrict__ Wo,
                                              const float* __restrict__ bo,
                                              float* __restrict__ out) {
    __shared__ float wsh[HID * NCLS];
    __shared__ float bsh[NCLS];
    int tid = threadIdx.x;
    for (int i = tid; i < HID * NCLS; i += 256) wsh[i] = Wo[i];
    if (tid < NCLS) bsh[tid] = bo[tid];
    __syncthreads();

    int w = (blockIdx.x * 256 + tid) >> 6;
    int lane = tid & 63;
    if (w >= N_NODES) return;

    float h0 = Hf[(long)w * HID + lane];
    float h1 = Hf[(long)w * HID + 64 + lane];

    float logit[NCLS];
    #pragma unroll
    for (int c = 0; c < NCLS; ++c) {
        float p = h0 * wsh[lane * NCLS + c] + h1 * wsh[(lane + 64) * NCLS + c];
        #pragma unroll
        for (int o = 32; o > 0; o >>= 1) p += __shfl_xor(p, o);
        logit[c] = p + bsh[c];
    }
    if (lane == 0) {
        float m = logit[0];
        #pragma unroll
        for (int c = 1; c < NCLS; ++c) m = fmaxf(m, logit[c]);
        float es[NCLS]; float ssum = 0.f;
        #pragma unroll
        for (int c = 0; c < NCLS; ++c) { es[c] = __expf(logit[c] - m); ssum += es[c]; }
        float inv = 1.f / ssum;
        #pragma unroll
        for (int c = 0; c < NCLS; ++c) out[(long)w * NCLS + c] = es[c] * inv;
    }
}

// ---------------- launch ----------------

static inline char* align256(char* p) {
    return (char*)(((uintptr_t)p + 255) & ~(uintptr_t)255);
}

extern "C" void kernel_launch(void* const* d_in, const int* in_sizes, int n_in,
                              void* d_out, int out_size, void* d_ws, size_t ws_size,
                              hipStream_t stream) {
    const float* x   = (const float*)d_in[0];
    const int*   ei  = (const int*)d_in[1];
    const float* W1  = (const float*)d_in[2];
    const float* b1  = (const float*)d_in[3];
    const float* W2  = (const float*)d_in[4];
    const float* b2  = (const float*)d_in[5];
    const float* Wo  = (const float*)d_in[6];
    const float* bo  = (const float*)d_in[7];
    float* out = (float*)d_out;

    const int* srcp = ei;            // edge_index[0]
    const int* dstp = ei + N_EDGES;  // edge_index[1]

    // workspace layout (256B-aligned chunks; big aligned arrays first)
    char* wsb = (char*)d_ws;
    float* hA = (float*)align256(wsb);                 wsb = (char*)(hA + (size_t)N_NODES * HID);
    float* hB = (float*)align256(wsb);                 wsb = (char*)(hB + (size_t)N_NODES * HID);
    __hip_bfloat16* W1T = (__hip_bfloat16*)align256(wsb); wsb = (char*)(W1T + 128 * 512);
    __hip_bfloat16* W2T = (__hip_bfloat16*)align256(wsb); wsb = (char*)(W2T + 128 * 128);
    int*   cnt = (int*)align256(wsb);                  wsb = (char*)(cnt + N_NODES);
    int*   off = (int*)align256(wsb);                  wsb = (char*)(off + N_NODES + 1);
    int*   cur = (int*)align256(wsb);                  wsb = (char*)(cur + N_NODES);
    int*   csr = (int*)align256(wsb);                  wsb = (char*)(csr + N_EDGES);
    float* dis = (float*)align256(wsb);                wsb = (char*)(dis + N_NODES);

    hipMemsetAsync(cnt, 0, sizeof(int) * N_NODES, stream);
    hipMemsetAsync(cur, 0, sizeof(int) * N_NODES, stream);

    int ebl = (N_EDGES + 255) / 256;
    int nbl = (N_NODES + 255) / 256;
    count_deg_k<<<ebl, 256, 0, stream>>>(dstp, cnt);
    compute_dis_k<<<nbl, 256, 0, stream>>>(cnt, dis);
    scan_k<<<1, 1024, 0, stream>>>(cnt, off);
    fill_csr_k<<<ebl, 256, 0, stream>>>(srcp, dstp, off, cur, csr);

    // weight transposes (tiny)
    transpose_cast_k<<<(128 * 512 + 255) / 256, 256, 0, stream>>>(W1, W1T, 500, 512);
    transpose_cast_k<<<(128 * 128 + 255) / 256, 256, 0, stream>>>(W2, W2T, 128, 128);

    int gblocks = (N_NODES + 63) / 64;   // 782
    int wblocks = (N_NODES + 3) / 4;     // 12500 (4 waves/block, 1 wave/node)

    // layer 1
    gemm_mfma_k<512, 500><<<gblocks, 256, 0, stream>>>(x, W1T, hA, N_NODES);
    agg_k<<<wblocks, 256, 0, stream>>>(hA, hB, off, csr, dis, b1);
    // layer 2
    gemm_mfma_k<128, 128><<<gblocks, 256, 0, stream>>>(hB, W2T, hA, N_NODES);
    agg_k<<<wblocks, 256, 0, stream>>>(hA, hB, off, csr, dis, b2);
    // head
    head_k<<<wblocks, 256, 0, stream>>>(hB, Wo, bo, out);
}

// Round 4
// 442.029 us; speedup vs baseline: 1.6587x; 1.0629x over previous
//
#include <hip/hip_runtime.h>
#include <hip/hip_bf16.h>
#include <stdint.h>

#define N_NODES 50000
#define N_EDGES 800000
#define F_IN    500
#define HID     128
#define NCLS    10

typedef __attribute__((ext_vector_type(8))) short bf16x8;
typedef __attribute__((ext_vector_type(4))) float f32x4;

__device__ __forceinline__ float bf_lo(uint32_t u) { return __uint_as_float(u << 16); }
__device__ __forceinline__ float bf_hi(uint32_t u) { return __uint_as_float(u & 0xffff0000u); }
__device__ __forceinline__ uint32_t bf_pack(float a, float b) {
    __hip_bfloat162 t; t.x = __float2bfloat16(a); t.y = __float2bfloat16(b);
    uint32_t r; __builtin_memcpy(&r, &t, 4); return r;
}

// ---------------- CSR build ----------------

__global__ __launch_bounds__(256) void count_deg_k(const int* __restrict__ dst, int* __restrict__ cnt) {
    int e = blockIdx.x * 256 + threadIdx.x;
    if (e < N_EDGES) atomicAdd(&cnt[dst[e]], 1);
}

// single block: block scan of counts -> off, plus dis = rsqrt(deg+1)
__global__ __launch_bounds__(1024) void scan_dis_k(const int* __restrict__ cnt,
                                                   int* __restrict__ off,
                                                   float* __restrict__ dis) {
    __shared__ int part[1024];
    const int PER = 52;  // 52*1024 >= 50000, %4==0
    int tid = threadIdx.x;
    int base = tid * PER;
    int vals[PER];
    #pragma unroll
    for (int i = 0; i < PER; i += 4) {
        int idx = base + i;
        int4 v = make_int4(0, 0, 0, 0);
        if (idx + 3 < N_NODES) {
            v = *(const int4*)&cnt[idx];
        } else {
            if (idx + 0 < N_NODES) v.x = cnt[idx + 0];
            if (idx + 1 < N_NODES) v.y = cnt[idx + 1];
            if (idx + 2 < N_NODES) v.z = cnt[idx + 2];
            if (idx + 3 < N_NODES) v.w = cnt[idx + 3];
        }
        vals[i + 0] = v.x; vals[i + 1] = v.y; vals[i + 2] = v.z; vals[i + 3] = v.w;
    }
    int s = 0;
    #pragma unroll
    for (int i = 0; i < PER; ++i) s += vals[i];
    part[tid] = s;
    __syncthreads();
    for (int o = 1; o < 1024; o <<= 1) {
        int v = (tid >= o) ? part[tid - o] : 0;
        __syncthreads();
        part[tid] += v;
        __syncthreads();
    }
    int run = part[tid] - s;  // exclusive prefix
    #pragma unroll
    for (int i = 0; i < PER; ++i) {
        int idx = base + i;
        if (idx < N_NODES) {
            off[idx] = run; run += vals[i];
            dis[idx] = rsqrtf((float)(vals[i] + 1));
        }
    }
    if (tid == 1023) off[N_NODES] = N_EDGES;
}

// fill via atomic decrement of cnt (cnt is dead afterwards) — no cur array/memset
__global__ __launch_bounds__(256) void fill_csr_k(const int* __restrict__ src,
                                                  const int* __restrict__ dst,
                                                  const int* __restrict__ off,
                                                  int* __restrict__ cnt,
                                                  int* __restrict__ csr) {
    int e = blockIdx.x * 256 + threadIdx.x;
    if (e < N_EDGES) {
        int d = dst[e];
        int old = atomicAdd(&cnt[d], -1);
        csr[off[d] + old - 1] = src[e];
    }
}

// ---------------- weight transpose+cast (both layers in one launch) ----------------
// W1 [500][128] -> W1T bf16 [128][512];  W2 [128][128] -> W2T bf16 [128][128]

__global__ __launch_bounds__(256) void transpose_both_k(const float* __restrict__ W1,
                                                        const float* __restrict__ W2,
                                                        __hip_bfloat16* __restrict__ W1T,
                                                        __hip_bfloat16* __restrict__ W2T) {
    int id = blockIdx.x * 256 + threadIdx.x;
    if (id < 128 * 512) {
        int n = id >> 9, k = id & 511;
        W1T[id] = (k < F_IN) ? __float2bfloat16(W1[(long)k * 128 + n]) : __float2bfloat16(0.f);
    } else {
        int id2 = id - 128 * 512;
        if (id2 < 128 * 128) {
            int n = id2 >> 7, k = id2 & 127;
            W2T[id2] = __float2bfloat16(W2[(long)k * 128 + n]);
        }
    }
}

// ---------------- MFMA GEMM: Out bf16 [M,128] = A[M,KREAL] @ BT[128,KPAD]^T ----------
// BM=64, BN=128, BK=64; 4 waves (2x2), wave tile 32x64. T14 reg-staged prefetch.
// Out is bf16, written coalesced via LDS overlay epilogue.

template<int KPAD, int KREAL, bool AF32>
__global__ __launch_bounds__(256) void gemm_mfma_k(const void* __restrict__ Av,
                                                   const __hip_bfloat16* __restrict__ BT,
                                                   __hip_bfloat16* __restrict__ Out, int M) {
    __shared__ __hip_bfloat16 smem[64 * 72 + 128 * 72];
    auto As = (__hip_bfloat16 (*)[72])smem;
    auto Bs = (__hip_bfloat16 (*)[72])(smem + 64 * 72);

    const int tid  = threadIdx.x;
    const int row0 = blockIdx.x * 64;
    const int wid  = tid >> 6, lane = tid & 63;
    const int wr   = (wid >> 1) * 32;
    const int wc   = (wid & 1) * 64;
    const int l15  = lane & 15;
    const int lk   = (lane >> 4) * 8;

    f32x4 acc[2][4];
    #pragma unroll
    for (int i = 0; i < 2; ++i)
        #pragma unroll
        for (int j = 0; j < 4; ++j) acc[i][j] = (f32x4){0.f, 0.f, 0.f, 0.f};

    const int arow = tid >> 2;          // 0..63
    const int aseg = (tid & 3) * 16;    // 0/16/32/48
    const int brow = tid >> 1;          // 0..127
    const int bseg = (tid & 1) * 32;    // 0/32
    const bool rowok = (row0 + arow) < M;

    bf16x8 a0, a1, b0, b1, b2v, b3;

    auto loadA = [&](int k0, bf16x8& r0, bf16x8& r1) {
        if (AF32) {
            const float* ap = (const float*)Av + (size_t)(row0 + arow) * KREAL + k0 + aseg;
            float v[16];
            if (rowok && (k0 + aseg + 16 <= KREAL)) {
                #pragma unroll
                for (int i = 0; i < 4; ++i) {
                    float4 f = ((const float4*)ap)[i];
                    v[4*i] = f.x; v[4*i+1] = f.y; v[4*i+2] = f.z; v[4*i+3] = f.w;
                }
            } else {
                #pragma unroll
                for (int i = 0; i < 16; ++i) {
                    int gk = k0 + aseg + i;
                    v[i] = (rowok && gk < KREAL) ? ap[i] : 0.f;
                }
            }
            __hip_bfloat16 bb[16];
            #pragma unroll
            for (int i = 0; i < 16; ++i) bb[i] = __float2bfloat16(v[i]);
            r0 = *(bf16x8*)&bb[0]; r1 = *(bf16x8*)&bb[8];
        } else {
            const __hip_bfloat16* ap = (const __hip_bfloat16*)Av + (size_t)(row0 + arow) * KREAL + k0 + aseg;
            if (rowok) { r0 = ((const bf16x8*)ap)[0]; r1 = ((const bf16x8*)ap)[1]; }
            else       { r0 = (bf16x8)(short)0;       r1 = (bf16x8)(short)0; }
        }
    };
    auto loadB = [&](int k0, bf16x8& r0, bf16x8& r1, bf16x8& r2, bf16x8& r3) {
        const __hip_bfloat16* bp = BT + (size_t)brow * KPAD + k0 + bseg;
        r0 = ((const bf16x8*)bp)[0]; r1 = ((const bf16x8*)bp)[1];
        r2 = ((const bf16x8*)bp)[2]; r3 = ((const bf16x8*)bp)[3];
    };

    loadA(0, a0, a1);
    loadB(0, b0, b1, b2v, b3);
    const int NT = KPAD / 64;
    for (int t = 0; t < NT; ++t) {
        *(bf16x8*)&As[arow][aseg]      = a0;
        *(bf16x8*)&As[arow][aseg + 8]  = a1;
        *(bf16x8*)&Bs[brow][bseg]      = b0;
        *(bf16x8*)&Bs[brow][bseg + 8]  = b1;
        *(bf16x8*)&Bs[brow][bseg + 16] = b2v;
        *(bf16x8*)&Bs[brow][bseg + 24] = b3;
        __syncthreads();
        if (t + 1 < NT) {                 // T14: issue next-tile loads before MFMA
            loadA((t + 1) * 64, a0, a1);
            loadB((t + 1) * 64, b0, b1, b2v, b3);
        }
        #pragma unroll
        for (int kk = 0; kk < 64; kk += 32) {
            bf16x8 af[2], bfr[4];
            #pragma unroll
            for (int i = 0; i < 2; ++i)
                af[i] = *(const bf16x8*)&As[wr + i * 16 + l15][kk + lk];
            #pragma unroll
            for (int j = 0; j < 4; ++j)
                bfr[j] = *(const bf16x8*)&Bs[wc + j * 16 + l15][kk + lk];
            #pragma unroll
            for (int i = 0; i < 2; ++i)
                #pragma unroll
                for (int j = 0; j < 4; ++j)
                    acc[i][j] = __builtin_amdgcn_mfma_f32_16x16x32_bf16(af[i], bfr[j], acc[i][j], 0, 0, 0);
        }
        __syncthreads();
    }

    // epilogue: acc -> bf16 LDS tile (overlays As/Bs) -> coalesced bf16x8 stores
    auto Cs = (__hip_bfloat16 (*)[136])smem;
    const int r4 = (lane >> 4) * 4;
    #pragma unroll
    for (int i = 0; i < 2; ++i)
        #pragma unroll
        for (int j = 0; j < 4; ++j)
            #pragma unroll
            for (int r = 0; r < 4; ++r)
                Cs[wr + i * 16 + r4 + r][wc + j * 16 + l15] = __float2bfloat16(acc[i][j][r]);
    __syncthreads();
    int trow = tid >> 2, tseg = (tid & 3) * 32;
    if (row0 + trow < M) {
        bf16x8* op = (bf16x8*)(Out + (size_t)(row0 + trow) * 128 + tseg);
        #pragma unroll
        for (int s = 0; s < 4; ++s) op[s] = *(bf16x8*)&Cs[trow][tseg + 8 * s];
    }
}

// ---------------- aggregation (bf16 in/out): one wave per node ----------------

__global__ __launch_bounds__(256) void agg_bf16_k(const __hip_bfloat16* __restrict__ Hin,
                                                  __hip_bfloat16* __restrict__ Hout,
                                                  const int* __restrict__ off,
                                                  const int* __restrict__ csr,
                                                  const float* __restrict__ dis,
                                                  const float* __restrict__ bias) {
    int w = (blockIdx.x * 256 + threadIdx.x) >> 6;
    int lane = threadIdx.x & 63;
    if (w >= N_NODES) return;
    int e0 = off[w], e1 = off[w + 1];
    float dn = dis[w];
    const uint32_t* hrow = (const uint32_t*)Hin;

    uint32_t u = hrow[(size_t)w * 64 + lane];
    float sw = dn * dn;
    float ax = bf_lo(u) * sw, ay = bf_hi(u) * sw;

    int e = e0;
    for (; e + 4 <= e1; e += 4) {
        int s0 = csr[e], s1 = csr[e + 1], s2 = csr[e + 2], s3 = csr[e + 3];
        float w0 = dis[s0] * dn, w1 = dis[s1] * dn, w2 = dis[s2] * dn, w3 = dis[s3] * dn;
        uint32_t m0 = hrow[(size_t)s0 * 64 + lane];
        uint32_t m1 = hrow[(size_t)s1 * 64 + lane];
        uint32_t m2 = hrow[(size_t)s2 * 64 + lane];
        uint32_t m3 = hrow[(size_t)s3 * 64 + lane];
        ax = fmaf(bf_lo(m0), w0, ax); ay = fmaf(bf_hi(m0), w0, ay);
        ax = fmaf(bf_lo(m1), w1, ax); ay = fmaf(bf_hi(m1), w1, ay);
        ax = fmaf(bf_lo(m2), w2, ax); ay = fmaf(bf_hi(m2), w2, ay);
        ax = fmaf(bf_lo(m3), w3, ax); ay = fmaf(bf_hi(m3), w3, ay);
    }
    for (; e < e1; ++e) {
        int s = csr[e];
        float wgt = dis[s] * dn;
        uint32_t m = hrow[(size_t)s * 64 + lane];
        ax = fmaf(bf_lo(m), wgt, ax);
        ay = fmaf(bf_hi(m), wgt, ay);
    }
    float2 bv = ((const float2*)bias)[lane];
    float ox = fmaxf(ax + bv.x, 0.f);
    float oy = fmaxf(ay + bv.y, 0.f);
    ((uint32_t*)Hout)[(size_t)w * 64 + lane] = bf_pack(ox, oy);
}

// ---------------- fused layer-2 aggregation + head (logits + softmax) ----------------

__global__ __launch_bounds__(256) void agg_head_k(const __hip_bfloat16* __restrict__ Hin,
                                                  const int* __restrict__ off,
                                                  const int* __restrict__ csr,
                                                  const float* __restrict__ dis,
                                                  const float* __restrict__ b2,
                                                  const float* __restrict__ Wo,
                                                  const float* __restrict__ bo,
                                                  float* __restrict__ out) {
    __shared__ float wsh[HID * NCLS];
    __shared__ float bsh[NCLS];
    int tid = threadIdx.x;
    for (int i = tid; i < HID * NCLS; i += 256) wsh[i] = Wo[i];
    if (tid < NCLS) bsh[tid] = bo[tid];
    __syncthreads();

    int w = (blockIdx.x * 256 + tid) >> 6;
    int lane = tid & 63;
    if (w >= N_NODES) return;

    // per-lane output weights (elements 2*lane, 2*lane+1) into regs
    float wreg0[NCLS], wreg1[NCLS];
    #pragma unroll
    for (int c = 0; c < NCLS; ++c) {
        wreg0[c] = wsh[(2 * lane) * NCLS + c];
        wreg1[c] = wsh[(2 * lane + 1) * NCLS + c];
    }

    int e0 = off[w], e1 = off[w + 1];
    float dn = dis[w];
    const uint32_t* hrow = (const uint32_t*)Hin;

    uint32_t u = hrow[(size_t)w * 64 + lane];
    float sw = dn * dn;
    float ax = bf_lo(u) * sw, ay = bf_hi(u) * sw;

    int e = e0;
    for (; e + 4 <= e1; e += 4) {
        int s0 = csr[e], s1 = csr[e + 1], s2 = csr[e + 2], s3 = csr[e + 3];
        float w0 = dis[s0] * dn, w1 = dis[s1] * dn, w2 = dis[s2] * dn, w3 = dis[s3] * dn;
        uint32_t m0 = hrow[(size_t)s0 * 64 + lane];
        uint32_t m1 = hrow[(size_t)s1 * 64 + lane];
        uint32_t m2 = hrow[(size_t)s2 * 64 + lane];
        uint32_t m3 = hrow[(size_t)s3 * 64 + lane];
        ax = fmaf(bf_lo(m0), w0, ax); ay = fmaf(bf_hi(m0), w0, ay);
        ax = fmaf(bf_lo(m1), w1, ax); ay = fmaf(bf_hi(m1), w1, ay);
        ax = fmaf(bf_lo(m2), w2, ax); ay = fmaf(bf_hi(m2), w2, ay);
        ax = fmaf(bf_lo(m3), w3, ax); ay = fmaf(bf_hi(m3), w3, ay);
    }
    for (; e < e1; ++e) {
        int s = csr[e];
        float wgt = dis[s] * dn;
        uint32_t m = hrow[(size_t)s * 64 + lane];
        ax = fmaf(bf_lo(m), wgt, ax);
        ay = fmaf(bf_hi(m), wgt, ay);
    }
    float2 bv = ((const float2*)b2)[lane];
    float hx = fmaxf(ax + bv.x, 0.f);
    float hy = fmaxf(ay + bv.y, 0.f);

    // logits: per-class wave reduction (f32 h — no extra rounding)
    float l[NCLS];
    #pragma unroll
    for (int c = 0; c < NCLS; ++c) {
        float p = fmaf(hx, wreg0[c], hy * wreg1[c]);
        #pragma unroll
        for (int o = 32; o > 0; o >>= 1) p += __shfl_xor(p, o);
        l[c] = p + bsh[c];
    }
    if (lane == 0) {
        float m = l[0];
        #pragma unroll
        for (int c = 1; c < NCLS; ++c) m = fmaxf(m, l[c]);
        float es[NCLS]; float ssum = 0.f;
        #pragma unroll
        for (int c = 0; c < NCLS; ++c) { es[c] = __expf(l[c] - m); ssum += es[c]; }
        float inv = 1.f / ssum;
        #pragma unroll
        for (int c = 0; c < NCLS; ++c) out[(size_t)w * NCLS + c] = es[c] * inv;
    }
}

// ---------------- launch ----------------

static inline char* align256(char* p) {
    return (char*)(((uintptr_t)p + 255) & ~(uintptr_t)255);
}

extern "C" void kernel_launch(void* const* d_in, const int* in_sizes, int n_in,
                              void* d_out, int out_size, void* d_ws, size_t ws_size,
                              hipStream_t stream) {
    const float* x   = (const float*)d_in[0];
    const int*   ei  = (const int*)d_in[1];
    const float* W1  = (const float*)d_in[2];
    const float* b1  = (const float*)d_in[3];
    const float* W2  = (const float*)d_in[4];
    const float* b2  = (const float*)d_in[5];
    const float* Wo  = (const float*)d_in[6];
    const float* bo  = (const float*)d_in[7];
    float* out = (float*)d_out;

    const int* srcp = ei;            // edge_index[0]
    const int* dstp = ei + N_EDGES;  // edge_index[1]

    char* wsb = (char*)d_ws;
    __hip_bfloat16* hA = (__hip_bfloat16*)align256(wsb);  wsb = (char*)(hA + (size_t)N_NODES * HID);
    __hip_bfloat16* hB = (__hip_bfloat16*)align256(wsb);  wsb = (char*)(hB + (size_t)N_NODES * HID);
    __hip_bfloat16* W1T = (__hip_bfloat16*)align256(wsb); wsb = (char*)(W1T + 128 * 512);
    __hip_bfloat16* W2T = (__hip_bfloat16*)align256(wsb); wsb = (char*)(W2T + 128 * 128);
    int*   cnt = (int*)align256(wsb);                     wsb = (char*)(cnt + N_NODES);
    int*   off = (int*)align256(wsb);                     wsb = (char*)(off + N_NODES + 1);
    int*   csr = (int*)align256(wsb);                     wsb = (char*)(csr + N_EDGES);
    float* dis = (float*)align256(wsb);                   wsb = (char*)(dis + N_NODES);

    hipMemsetAsync(cnt, 0, sizeof(int) * N_NODES, stream);

    int ebl = (N_EDGES + 255) / 256;
    count_deg_k<<<ebl, 256, 0, stream>>>(dstp, cnt);
    scan_dis_k<<<1, 1024, 0, stream>>>(cnt, off, dis);
    fill_csr_k<<<ebl, 256, 0, stream>>>(srcp, dstp, off, cnt, csr);
    transpose_both_k<<<(128 * 512 + 128 * 128 + 255) / 256, 256, 0, stream>>>(W1, W2, W1T, W2T);

    int gblocks = (N_NODES + 63) / 64;   // 782
    int wblocks = (N_NODES + 3) / 4;     // 12500

    gemm_mfma_k<512, 500, true><<<gblocks, 256, 0, stream>>>(x, W1T, hA, N_NODES);
    agg_bf16_k<<<wblocks, 256, 0, stream>>>(hA, hB, off, csr, dis, b1);
    gemm_mfma_k<128, 128, false><<<gblocks, 256, 0, stream>>>(hB, W2T, hA, N_NODES);
    agg_head_k<<<wblocks, 256, 0, stream>>>(hA, off, csr, dis, b2, Wo, bo, out);
}

// Round 11
// 432.521 us; speedup vs baseline: 1.6952x; 1.0220x over previous
//
#include <hip/hip_runtime.h>
#include <hip/hip_bf16.h>
#include <stdint.h>

#define N_NODES 50000
#define N_EDGES 800000
#define F_IN    500
#define HID     128
#define NCLS    10

typedef __attribute__((ext_vector_type(8))) short bf16x8;
typedef __attribute__((ext_vector_type(4))) float f32x4;

__device__ __forceinline__ float bf_lo(uint32_t u) { return __uint_as_float(u << 16); }
__device__ __forceinline__ float bf_hi(uint32_t u) { return __uint_as_float(u & 0xffff0000u); }
__device__ __forceinline__ uint32_t bf_pack(float a, float b) {
    __hip_bfloat162 t; t.x = __float2bfloat16(a); t.y = __float2bfloat16(b);
    uint32_t r; __builtin_memcpy(&r, &t, 4); return r;
}

// ---------------- CSR build ----------------

__global__ __launch_bounds__(256) void count_deg_k(const int* __restrict__ dst, int* __restrict__ cnt) {
    int e = blockIdx.x * 256 + threadIdx.x;
    if (e < N_EDGES) atomicAdd(&cnt[dst[e]], 1);
}

// block 0: scan of counts -> off, dis = rsqrt(deg+1).  blocks 1..80: weight transpose+cast.
__global__ __launch_bounds__(1024) void scan_dis_transpose_k(const int* __restrict__ cnt,
                                                             int* __restrict__ off,
                                                             float* __restrict__ dis,
                                                             const float* __restrict__ W1,
                                                             const float* __restrict__ W2,
                                                             __hip_bfloat16* __restrict__ W1T,
                                                             __hip_bfloat16* __restrict__ W2T) {
    int tid = threadIdx.x;
    if (blockIdx.x != 0) {
        int id = (blockIdx.x - 1) * 1024 + tid;   // [0, 81920)
        if (id < 128 * 512) {
            int n = id >> 9, k = id & 511;
            W1T[id] = (k < F_IN) ? __float2bfloat16(W1[(long)k * 128 + n]) : __float2bfloat16(0.f);
        } else {
            int id2 = id - 128 * 512;
            if (id2 < 128 * 128) {
                int n = id2 >> 7, k = id2 & 127;
                W2T[id2] = __float2bfloat16(W2[(long)k * 128 + n]);
            }
        }
        return;
    }
    __shared__ int part[1024];
    const int PER = 52;  // 52*1024 >= 50000, %4==0
    int base = tid * PER;
    int vals[PER];
    #pragma unroll
    for (int i = 0; i < PER; i += 4) {
        int idx = base + i;
        int4 v = make_int4(0, 0, 0, 0);
        if (idx + 3 < N_NODES) {
            v = *(const int4*)&cnt[idx];
        } else {
            if (idx + 0 < N_NODES) v.x = cnt[idx + 0];
            if (idx + 1 < N_NODES) v.y = cnt[idx + 1];
            if (idx + 2 < N_NODES) v.z = cnt[idx + 2];
            if (idx + 3 < N_NODES) v.w = cnt[idx + 3];
        }
        vals[i + 0] = v.x; vals[i + 1] = v.y; vals[i + 2] = v.z; vals[i + 3] = v.w;
    }
    int s = 0;
    #pragma unroll
    for (int i = 0; i < PER; ++i) s += vals[i];
    part[tid] = s;
    __syncthreads();
    for (int o = 1; o < 1024; o <<= 1) {
        int v = (tid >= o) ? part[tid - o] : 0;
        __syncthreads();
        part[tid] += v;
        __syncthreads();
    }
    int run = part[tid] - s;  // exclusive prefix
    #pragma unroll
    for (int i = 0; i < PER; ++i) {
        int idx = base + i;
        if (idx < N_NODES) {
            off[idx] = run; run += vals[i];
            dis[idx] = rsqrtf((float)(vals[i] + 1));
        }
    }
    if (tid == 1023) off[N_NODES] = N_EDGES;
}

// fill via atomic decrement of cnt (cnt is dead afterwards)
__global__ __launch_bounds__(256) void fill_csr_k(const int* __restrict__ src,
                                                  const int* __restrict__ dst,
                                                  const int* __restrict__ off,
                                                  int* __restrict__ cnt,
                                                  int* __restrict__ csr) {
    int e = blockIdx.x * 256 + threadIdx.x;
    if (e < N_EDGES) {
        int d = dst[e];
        int old = atomicAdd(&cnt[d], -1);
        csr[off[d] + old - 1] = src[e];
    }
}

// ---------------- MFMA GEMM: Out bf16 [M,128] = A[M,KREAL] @ BT[128,KPAD]^T ----------
// BM=64, BN=128, BK=64; 4 waves (2x2), wave tile 32x64. Reg-staged prefetch.

template<int KPAD, int KREAL, bool AF32>
__global__ __launch_bounds__(256) void gemm_mfma_k(const void* __restrict__ Av,
                                                   const __hip_bfloat16* __restrict__ BT,
                                                   __hip_bfloat16* __restrict__ Out, int M) {
    __shared__ __hip_bfloat16 smem[64 * 72 + 128 * 72];
    auto As = (__hip_bfloat16 (*)[72])smem;
    auto Bs = (__hip_bfloat16 (*)[72])(smem + 64 * 72);

    const int tid  = threadIdx.x;
    const int row0 = blockIdx.x * 64;
    const int wid  = tid >> 6, lane = tid & 63;
    const int wr   = (wid >> 1) * 32;
    const int wc   = (wid & 1) * 64;
    const int l15  = lane & 15;
    const int lk   = (lane >> 4) * 8;

    f32x4 acc[2][4];
    #pragma unroll
    for (int i = 0; i < 2; ++i)
        #pragma unroll
        for (int j = 0; j < 4; ++j) acc[i][j] = (f32x4){0.f, 0.f, 0.f, 0.f};

    const int arow = tid >> 2;          // 0..63
    const int aseg = (tid & 3) * 16;    // 0/16/32/48
    const int brow = tid >> 1;          // 0..127
    const int bseg = (tid & 1) * 32;    // 0/32
    const bool rowok = (row0 + arow) < M;

    bf16x8 a0, a1, b0, b1, b2v, b3;

    auto loadA = [&](int k0, bf16x8& r0, bf16x8& r1) {
        if (AF32) {
            const float* ap = (const float*)Av + (size_t)(row0 + arow) * KREAL + k0 + aseg;
            float v[16];
            if (rowok && (k0 + aseg + 16 <= KREAL)) {
                #pragma unroll
                for (int i = 0; i < 4; ++i) {
                    float4 f = ((const float4*)ap)[i];
                    v[4*i] = f.x; v[4*i+1] = f.y; v[4*i+2] = f.z; v[4*i+3] = f.w;
                }
            } else {
                #pragma unroll
                for (int i = 0; i < 16; ++i) {
                    int gk = k0 + aseg + i;
                    v[i] = (rowok && gk < KREAL) ? ap[i] : 0.f;
                }
            }
            __hip_bfloat16 bb[16];
            #pragma unroll
            for (int i = 0; i < 16; ++i) bb[i] = __float2bfloat16(v[i]);
            r0 = *(bf16x8*)&bb[0]; r1 = *(bf16x8*)&bb[8];
        } else {
            const __hip_bfloat16* ap = (const __hip_bfloat16*)Av + (size_t)(row0 + arow) * KREAL + k0 + aseg;
            if (rowok) { r0 = ((const bf16x8*)ap)[0]; r1 = ((const bf16x8*)ap)[1]; }
            else       { r0 = (bf16x8)(short)0;       r1 = (bf16x8)(short)0; }
        }
    };
    auto loadB = [&](int k0, bf16x8& r0, bf16x8& r1, bf16x8& r2, bf16x8& r3) {
        const __hip_bfloat16* bp = BT + (size_t)brow * KPAD + k0 + bseg;
        r0 = ((const bf16x8*)bp)[0]; r1 = ((const bf16x8*)bp)[1];
        r2 = ((const bf16x8*)bp)[2]; r3 = ((const bf16x8*)bp)[3];
    };

    loadA(0, a0, a1);
    loadB(0, b0, b1, b2v, b3);
    const int NT = KPAD / 64;
    for (int t = 0; t < NT; ++t) {
        *(bf16x8*)&As[arow][aseg]      = a0;
        *(bf16x8*)&As[arow][aseg + 8]  = a1;
        *(bf16x8*)&Bs[brow][bseg]      = b0;
        *(bf16x8*)&Bs[brow][bseg + 8]  = b1;
        *(bf16x8*)&Bs[brow][bseg + 16] = b2v;
        *(bf16x8*)&Bs[brow][bseg + 24] = b3;
        __syncthreads();
        if (t + 1 < NT) {
            loadA((t + 1) * 64, a0, a1);
            loadB((t + 1) * 64, b0, b1, b2v, b3);
        }
        #pragma unroll
        for (int kk = 0; kk < 64; kk += 32) {
            bf16x8 af[2], bfr[4];
            #pragma unroll
            for (int i = 0; i < 2; ++i)
                af[i] = *(const bf16x8*)&As[wr + i * 16 + l15][kk + lk];
            #pragma unroll
            for (int j = 0; j < 4; ++j)
                bfr[j] = *(const bf16x8*)&Bs[wc + j * 16 + l15][kk + lk];
            #pragma unroll
            for (int i = 0; i < 2; ++i)
                #pragma unroll
                for (int j = 0; j < 4; ++j)
                    acc[i][j] = __builtin_amdgcn_mfma_f32_16x16x32_bf16(af[i], bfr[j], acc[i][j], 0, 0, 0);
        }
        __syncthreads();
    }

    // epilogue: acc -> bf16 LDS tile -> coalesced bf16x8 stores
    auto Cs = (__hip_bfloat16 (*)[136])smem;
    const int r4 = (lane >> 4) * 4;
    #pragma unroll
    for (int i = 0; i < 2; ++i)
        #pragma unroll
        for (int j = 0; j < 4; ++j)
            #pragma unroll
            for (int r = 0; r < 4; ++r)
                Cs[wr + i * 16 + r4 + r][wc + j * 16 + l15] = __float2bfloat16(acc[i][j][r]);
    __syncthreads();
    int trow = tid >> 2, tseg = (tid & 3) * 32;
    if (row0 + trow < M) {
        bf16x8* op = (bf16x8*)(Out + (size_t)(row0 + trow) * 128 + tseg);
        #pragma unroll
        for (int s = 0; s < 4; ++s) op[s] = *(bf16x8*)&Cs[trow][tseg + 8 * s];
    }
}

// ---------------- aggregation core: edge-preload + shfl broadcast + 8 gathers in flight
// wave = node; lane holds feature pair (2*lane, 2*lane+1).

__device__ __forceinline__ void agg_core(const uint32_t* __restrict__ hrow,
                                         const int* __restrict__ csr,
                                         const float* __restrict__ dis,
                                         int e0, int e1, int lane, float dn,
                                         float& ax, float& ay) {
    int deg = e1 - e0;
    for (int base = 0; base < deg; base += 64) {
        int nb = min(64, deg - base);
        int sl = 0; float wl = 0.f;
        if (lane < nb) {               // parallel preload of edge ids + weights
            sl = csr[e0 + base + lane];
            wl = dis[sl] * dn;
        }
        for (int j = 0; j < nb; j += 8) {
            uint32_t m[8]; float ww[8];
            #pragma unroll
            for (int k = 0; k < 8; ++k) {
                int   sk = __shfl(sl, j + k);     // lanes >= nb hold (0, 0.0) -> safe
                float wk = __shfl(wl, j + k);
                m[k]  = hrow[(size_t)sk * 64 + lane];
                ww[k] = wk;
            }
            #pragma unroll
            for (int k = 0; k < 8; ++k) {
                ax = fmaf(bf_lo(m[k]), ww[k], ax);
                ay = fmaf(bf_hi(m[k]), ww[k], ay);
            }
        }
    }
}

__global__ __launch_bounds__(256) void agg_bf16_k(const __hip_bfloat16* __restrict__ Hin,
                                                  __hip_bfloat16* __restrict__ Hout,
                                                  const int* __restrict__ off,
                                                  const int* __restrict__ csr,
                                                  const float* __restrict__ dis,
                                                  const float* __restrict__ bias) {
    int w = (blockIdx.x * 256 + threadIdx.x) >> 6;
    int lane = threadIdx.x & 63;
    if (w >= N_NODES) return;
    int e0 = off[w], e1 = off[w + 1];
    float dn = dis[w];
    const uint32_t* hrow = (const uint32_t*)Hin;

    uint32_t u = hrow[(size_t)w * 64 + lane];
    float sw = dn * dn;
    float ax = bf_lo(u) * sw, ay = bf_hi(u) * sw;

    agg_core(hrow, csr, dis, e0, e1, lane, dn, ax, ay);

    float2 bv = ((const float2*)bias)[lane];
    float ox = fmaxf(ax + bv.x, 0.f);
    float oy = fmaxf(ay + bv.y, 0.f);
    ((uint32_t*)Hout)[(size_t)w * 64 + lane] = bf_pack(ox, oy);
}

// ---------------- fused layer-2 aggregation + head (logits + softmax) ----------------

__global__ __launch_bounds__(256) void agg_head_k(const __hip_bfloat16* __restrict__ Hin,
                                                  const int* __restrict__ off,
                                                  const int* __restrict__ csr,
                                                  const float* __restrict__ dis,
                                                  const float* __restrict__ b2,
                                                  const float* __restrict__ Wo,
                                                  const float* __restrict__ bo,
                                                  float* __restrict__ out) {
    __shared__ float wsh[HID * NCLS];
    __shared__ float bsh[NCLS];
    int tid = threadIdx.x;
    for (int i = tid; i < HID * NCLS; i += 256) wsh[i] = Wo[i];
    if (tid < NCLS) bsh[tid] = bo[tid];
    __syncthreads();

    int w = (blockIdx.x * 256 + tid) >> 6;
    int lane = tid & 63;
    if (w >= N_NODES) return;

    float wreg0[NCLS], wreg1[NCLS];
    #pragma unroll
    for (int c = 0; c < NCLS; ++c) {
        wreg0[c] = wsh[(2 * lane) * NCLS + c];
        wreg1[c] = wsh[(2 * lane + 1) * NCLS + c];
    }

    int e0 = off[w], e1 = off[w + 1];
    float dn = dis[w];
    const uint32_t* hrow = (const uint32_t*)Hin;

    uint32_t u = hrow[(size_t)w * 64 + lane];
    float sw = dn * dn;
    float ax = bf_lo(u) * sw, ay = bf_hi(u) * sw;

    agg_core(hrow, csr, dis, e0, e1, lane, dn, ax, ay);

    float2 bv = ((const float2*)b2)[lane];
    float hx = fmaxf(ax + bv.x, 0.f);
    float hy = fmaxf(ay + bv.y, 0.f);

    // logits: per-class wave butterfly (all lanes end with the total)
    float l[NCLS];
    #pragma unroll
    for (int c = 0; c < NCLS; ++c) {
        float p = fmaf(hx, wreg0[c], hy * wreg1[c]);
        #pragma unroll
        for (int o = 32; o > 0; o >>= 1) p += __shfl_xor(p, o);
        l[c] = p + bsh[c];
    }
    // softmax redundantly on all lanes (no divergent serial section)
    float m = l[0];
    #pragma unroll
    for (int c = 1; c < NCLS; ++c) m = fmaxf(m, l[c]);
    float es[NCLS]; float ssum = 0.f;
    #pragma unroll
    for (int c = 0; c < NCLS; ++c) { es[c] = __expf(l[c] - m); ssum += es[c]; }
    float inv = 1.f / ssum;
    float vout = 0.f;
    #pragma unroll
    for (int c = 0; c < NCLS; ++c) vout = (lane == c) ? es[c] * inv : vout;
    if (lane < NCLS) out[(size_t)w * NCLS + lane] = vout;
}

// ---------------- launch ----------------

static inline char* align256(char* p) {
    return (char*)(((uintptr_t)p + 255) & ~(uintptr_t)255);
}

extern "C" void kernel_launch(void* const* d_in, const int* in_sizes, int n_in,
                              void* d_out, int out_size, void* d_ws, size_t ws_size,
                              hipStream_t stream) {
    const float* x   = (const float*)d_in[0];
    const int*   ei  = (const int*)d_in[1];
    const float* W1  = (const float*)d_in[2];
    const float* b1  = (const float*)d_in[3];
    const float* W2  = (const float*)d_in[4];
    const float* b2  = (const float*)d_in[5];
    const float* Wo  = (const float*)d_in[6];
    const float* bo  = (const float*)d_in[7];
    float* out = (float*)d_out;

    const int* srcp = ei;            // edge_index[0]
    const int* dstp = ei + N_EDGES;  // edge_index[1]

    char* wsb = (char*)d_ws;
    __hip_bfloat16* hA = (__hip_bfloat16*)align256(wsb);  wsb = (char*)(hA + (size_t)N_NODES * HID);
    __hip_bfloat16* hB = (__hip_bfloat16*)align256(wsb);  wsb = (char*)(hB + (size_t)N_NODES * HID);
    __hip_bfloat16* W1T = (__hip_bfloat16*)align256(wsb); wsb = (char*)(W1T + 128 * 512);
    __hip_bfloat16* W2T = (__hip_bfloat16*)align256(wsb); wsb = (char*)(W2T + 128 * 128);
    int*   cnt = (int*)align256(wsb);                     wsb = (char*)(cnt + N_NODES);
    int*   off = (int*)align256(wsb);                     wsb = (char*)(off + N_NODES + 1);
    int*   csr = (int*)align256(wsb);                     wsb = (char*)(csr + N_EDGES);
    float* dis = (float*)align256(wsb);                   wsb = (char*)(dis + N_NODES);

    hipMemsetAsync(cnt, 0, sizeof(int) * N_NODES, stream);

    int ebl = (N_EDGES + 255) / 256;
    count_deg_k<<<ebl, 256, 0, stream>>>(dstp, cnt);
    scan_dis_transpose_k<<<81, 1024, 0, stream>>>(cnt, off, dis, W1, W2, W1T, W2T);
    fill_csr_k<<<ebl, 256, 0, stream>>>(srcp, dstp, off, cnt, csr);

    int gblocks = (N_NODES + 63) / 64;   // 782
    int wblocks = (N_NODES + 3) / 4;     // 12500

    gemm_mfma_k<512, 500, true><<<gblocks, 256, 0, stream>>>(x, W1T, hA, N_NODES);
    agg_bf16_k<<<wblocks, 256, 0, stream>>>(hA, hB, off, csr, dis, b1);
    gemm_mfma_k<128, 128, false><<<gblocks, 256, 0, stream>>>(hB, W2T, hA, N_NODES);
    agg_head_k<<<wblocks, 256, 0, stream>>>(hA, off, csr, dis, b2, Wo, bo, out);
}